// Round 10
// baseline (71.252 us; speedup 1.0000x reference)
//
#include <hip/hip_runtime.h>
#include <math.h>

#define BB 512
#define SS 200
#define DD 64
#define VV 100000

__device__ __forceinline__ float gauss_pdf(float xx, float mu, float sg) {
    float z = (xx - mu) / sg;
    return expf(-0.5f * z * z - logf(sg) - 0.9189385332046727f);
}

// tanh(x) = 1 - 2/(exp(2x)+1). Branch-free: exp->inf gives 1, exp->0 gives -1.
__device__ __forceinline__ float fast_tanh(float x) {
    float e = __expf(2.f * x);
    return 1.f - 2.f / (e + 1.f);
}

// v8: intra-block wave role-split. Waves 0-1 compute (2 s-rows per thread,
// each broadcast Wq read serves 8 FMAs); waves 2-3 stream the block's 400 KB
// of zeros with regular float4 stores (v6 proved these sustain HBM rate; the
// round-9 NT/block-split variant did not). In-order waves cannot pass their
// own pending stores, so the drain parks ONLY waves 2-3 while waves 0-1 run
// the GEMV on the same CU -> store drain and compute finally overlap.
__global__ __launch_bounds__(256, 2) void fused_v8(
    const float* __restrict__ x, const int* __restrict__ x_ids,
    const float* __restrict__ tg, const int* __restrict__ cla,
    const float* __restrict__ Wq, const float* __restrict__ bq,
    const float* __restrict__ Wk, const float* __restrict__ bk,
    const float* __restrict__ wv, const float* __restrict__ bv,
    const float* __restrict__ theta, float* __restrict__ out)
{
    const int b    = blockIdx.x;
    const int tid  = threadIdx.x;
    const int lane = tid & 63;
    const int wave = tid >> 6;

    __shared__ float sWq[DD * DD];   // 16 KB, row-major [j][d]
    __shared__ float sx0[DD];
    __shared__ float sKp[4][DD];
    __shared__ float sK[DD];
    __shared__ float sWv[DD];
    __shared__ float sScore[SS];
    __shared__ float sRed[8];
    __shared__ float sTh[17];

    const float* __restrict__ xb = x + (size_t)b * SS * DD;
    float* __restrict__ orow = out + (size_t)b * VV;

    // ---- compute threads' TWO x-rows into named float4 regs ----
    // thread t < 128: row A = t; row B = t + 128 (valid iff t < 72)
    float4 xA0={0,0,0,0},xA1={0,0,0,0},xA2={0,0,0,0},xA3={0,0,0,0},
           xA4={0,0,0,0},xA5={0,0,0,0},xA6={0,0,0,0},xA7={0,0,0,0},
           xA8={0,0,0,0},xA9={0,0,0,0},xA10={0,0,0,0},xA11={0,0,0,0},
           xA12={0,0,0,0},xA13={0,0,0,0},xA14={0,0,0,0},xA15={0,0,0,0};
    float4 xB0={0,0,0,0},xB1={0,0,0,0},xB2={0,0,0,0},xB3={0,0,0,0},
           xB4={0,0,0,0},xB5={0,0,0,0},xB6={0,0,0,0},xB7={0,0,0,0},
           xB8={0,0,0,0},xB9={0,0,0,0},xB10={0,0,0,0},xB11={0,0,0,0},
           xB12={0,0,0,0},xB13={0,0,0,0},xB14={0,0,0,0},xB15={0,0,0,0};
    if (tid < 128) {
        const float4* __restrict__ xp = (const float4*)(xb + tid * DD);
        xA0=xp[0]; xA1=xp[1]; xA2=xp[2]; xA3=xp[3];
        xA4=xp[4]; xA5=xp[5]; xA6=xp[6]; xA7=xp[7];
        xA8=xp[8]; xA9=xp[9]; xA10=xp[10]; xA11=xp[11];
        xA12=xp[12]; xA13=xp[13]; xA14=xp[14]; xA15=xp[15];
    }
    if (tid < SS - 128) {   // tid < 72
        const float4* __restrict__ xq = (const float4*)(xb + (tid + 128) * DD);
        xB0=xq[0]; xB1=xq[1]; xB2=xq[2]; xB3=xq[3];
        xB4=xq[4]; xB5=xq[5]; xB6=xq[6]; xB7=xq[7];
        xB8=xq[8]; xB9=xq[9]; xB10=xq[10]; xB11=xq[11];
        xB12=xq[12]; xB13=xq[13]; xB14=xq[14]; xB15=xq[15];
    }

    // ---- stage Wq / x0 / wv / theta (all 256 threads) ----
    {
        const float4* __restrict__ Wq4 = (const float4*)Wq;
        float4* __restrict__ sWq4 = (float4*)sWq;
        #pragma unroll
        for (int c = 0; c < 4; ++c) sWq4[tid + 256 * c] = Wq4[tid + 256 * c];
    }
    if (tid < DD) sx0[tid] = xb[tid];
    if (tid >= 64 && tid < 128) sWv[tid - 64] = wv[tid - 64];
    if (tid >= 128 && tid < 145) sTh[tid - 128] = theta[tid - 128];
    __syncthreads();

    // ---- k partials: wave w covers j in [16w, 16w+16); lane = d ----
    {
        float acc = 0.f;
        #pragma unroll
        for (int jj = 0; jj < 16; ++jj) {
            int j = wave * 16 + jj;
            acc = fmaf(sx0[j], Wk[j * DD + lane], acc);
        }
        sKp[wave][lane] = acc;
    }
    __syncthreads();
    if (tid < DD)
        sK[tid] = sKp[0][tid] + sKp[1][tid] + sKp[2][tid] + sKp[3][tid]
                + bq[tid] + bk[tid];
    __syncthreads();
    // ======== roles diverge here; re-merge at the pre-softmax barrier ======

    if (tid >= 128) {
        // ---- store role (waves 2-3): zero this block's 400 KB row ----
        float4* __restrict__ orow4 = (float4*)orow;
        const float4 z4 = make_float4(0.f, 0.f, 0.f, 0.f);
        for (int i = tid - 128; i < VV / 4; i += 128)
            orow4[i] = z4;
    } else {
        // ---- compute role (waves 0-1): 2-row fused GEMV + tanh + wv-dot ----
        const float4* __restrict__ W4 = (const float4*)sWq; // [j][16 x float4]
        float scA = 0.f, scB = 0.f;
        for (int g = 0; g < 16; ++g) {        // d-group: d = 4g..4g+3
            float a0=0.f,a1=0.f,a2=0.f,a3=0.f, b0=0.f,b1=0.f,b2=0.f,b3=0.f;
#define STEP(J, XA, XB) { float4 w = W4[(J)*16 + g]; \
    a0 = fmaf(XA, w.x, a0); a1 = fmaf(XA, w.y, a1); \
    a2 = fmaf(XA, w.z, a2); a3 = fmaf(XA, w.w, a3); \
    b0 = fmaf(XB, w.x, b0); b1 = fmaf(XB, w.y, b1); \
    b2 = fmaf(XB, w.z, b2); b3 = fmaf(XB, w.w, b3); }
            STEP(0, xA0.x,xB0.x)  STEP(1, xA0.y,xB0.y)
            STEP(2, xA0.z,xB0.z)  STEP(3, xA0.w,xB0.w)
            STEP(4, xA1.x,xB1.x)  STEP(5, xA1.y,xB1.y)
            STEP(6, xA1.z,xB1.z)  STEP(7, xA1.w,xB1.w)
            STEP(8, xA2.x,xB2.x)  STEP(9, xA2.y,xB2.y)
            STEP(10,xA2.z,xB2.z)  STEP(11,xA2.w,xB2.w)
            STEP(12,xA3.x,xB3.x)  STEP(13,xA3.y,xB3.y)
            STEP(14,xA3.z,xB3.z)  STEP(15,xA3.w,xB3.w)
            STEP(16,xA4.x,xB4.x)  STEP(17,xA4.y,xB4.y)
            STEP(18,xA4.z,xB4.z)  STEP(19,xA4.w,xB4.w)
            STEP(20,xA5.x,xB5.x)  STEP(21,xA5.y,xB5.y)
            STEP(22,xA5.z,xB5.z)  STEP(23,xA5.w,xB5.w)
            STEP(24,xA6.x,xB6.x)  STEP(25,xA6.y,xB6.y)
            STEP(26,xA6.z,xB6.z)  STEP(27,xA6.w,xB6.w)
            STEP(28,xA7.x,xB7.x)  STEP(29,xA7.y,xB7.y)
            STEP(30,xA7.z,xB7.z)  STEP(31,xA7.w,xB7.w)
            STEP(32,xA8.x,xB8.x)  STEP(33,xA8.y,xB8.y)
            STEP(34,xA8.z,xB8.z)  STEP(35,xA8.w,xB8.w)
            STEP(36,xA9.x,xB9.x)  STEP(37,xA9.y,xB9.y)
            STEP(38,xA9.z,xB9.z)  STEP(39,xA9.w,xB9.w)
            STEP(40,xA10.x,xB10.x) STEP(41,xA10.y,xB10.y)
            STEP(42,xA10.z,xB10.z) STEP(43,xA10.w,xB10.w)
            STEP(44,xA11.x,xB11.x) STEP(45,xA11.y,xB11.y)
            STEP(46,xA11.z,xB11.z) STEP(47,xA11.w,xB11.w)
            STEP(48,xA12.x,xB12.x) STEP(49,xA12.y,xB12.y)
            STEP(50,xA12.z,xB12.z) STEP(51,xA12.w,xB12.w)
            STEP(52,xA13.x,xB13.x) STEP(53,xA13.y,xB13.y)
            STEP(54,xA13.z,xB13.z) STEP(55,xA13.w,xB13.w)
            STEP(56,xA14.x,xB14.x) STEP(57,xA14.y,xB14.y)
            STEP(58,xA14.z,xB14.z) STEP(59,xA14.w,xB14.w)
            STEP(60,xA15.x,xB15.x) STEP(61,xA15.y,xB15.y)
            STEP(62,xA15.z,xB15.z) STEP(63,xA15.w,xB15.w)
#undef STEP
            const int d = 4 * g;
            scA = fmaf(fast_tanh(a0 + sK[d+0]), sWv[d+0], scA);
            scA = fmaf(fast_tanh(a1 + sK[d+1]), sWv[d+1], scA);
            scA = fmaf(fast_tanh(a2 + sK[d+2]), sWv[d+2], scA);
            scA = fmaf(fast_tanh(a3 + sK[d+3]), sWv[d+3], scA);
            scB = fmaf(fast_tanh(b0 + sK[d+0]), sWv[d+0], scB);
            scB = fmaf(fast_tanh(b1 + sK[d+1]), sWv[d+1], scB);
            scB = fmaf(fast_tanh(b2 + sK[d+2]), sWv[d+2], scB);
            scB = fmaf(fast_tanh(b3 + sK[d+3]), sWv[d+3], scB);
        }
        {
            int idA = x_ids[b * SS + tid];
            sScore[tid] = (idA == 0 || idA == 1) ? -INFINITY : (scA + bv[0]);
        }
        if (tid < SS - 128) {
            int idB = x_ids[b * SS + tid + 128];
            sScore[tid + 128] =
                (idB == 0 || idB == 1) ? -INFINITY : (scB + bv[0]);
        }
    }
    __syncthreads();   // scores ready AND this block's zero-stores drained

    // ---- block softmax over 200 scores (tid == s) ----
    float sc = (tid < SS) ? sScore[tid] : -INFINITY;
    float m = sc;
    #pragma unroll
    for (int off = 32; off > 0; off >>= 1) m = fmaxf(m, __shfl_xor(m, off));
    if (lane == 0) sRed[wave] = m;
    __syncthreads();
    const float M = fmaxf(fmaxf(sRed[0], sRed[1]), fmaxf(sRed[2], sRed[3]));
    float e = (tid < SS) ? expf(sc - M) : 0.f;
    float ssum = e;
    #pragma unroll
    for (int off = 32; off > 0; off >>= 1) ssum += __shfl_xor(ssum, off);
    if (lane == 0) sRed[4 + wave] = ssum;
    __syncthreads();
    const float Z = sRed[4] + sRed[5] + sRed[6] + sRed[7];

    const float wpg = sTh[6];

    // p_repeat scatter into this block's own (already-zeroed) row
    if (tid < SS && e > 0.f) {
        int id = x_ids[b * SS + tid];
        atomicAdd(orow + id, (1.f - wpg) * (e / Z));
    }

    // p_gap scatter at ids x_ids[:, 1:]
    if (tid < SS - 1) {
        float t  = tg[b * (SS - 1) + tid];
        int   c  = cla[b * (SS - 1) + tid];
        float c0 = (c == 0) ? t : 180.f;
        float c1 = (c == 1) ? t : 180.f;
        float c2 = (c == 2) ? t : 180.f;
        float g = sTh[0] * gauss_pdf(c0, sTh[7],  sTh[8])
                + sTh[1] * gauss_pdf(c1, sTh[9],  sTh[10])
                + sTh[2] * gauss_pdf(c1, sTh[11], sTh[12])
                + sTh[3] * gauss_pdf(c2, sTh[13], sTh[14])
                + sTh[4] * powf(c2, sTh[15]);
        int id = x_ids[b * SS + tid + 1];
        atomicAdd(orow + id, wpg * g);
    }
}

extern "C" void kernel_launch(void* const* d_in, const int* in_sizes, int n_in,
                              void* d_out, int out_size, void* d_ws, size_t ws_size,
                              hipStream_t stream) {
    const float* x     = (const float*)d_in[0];
    const int*   x_ids = (const int*)d_in[1];
    const float* tgp   = (const float*)d_in[2];
    const int*   cl    = (const int*)d_in[3];
    const float* Wq    = (const float*)d_in[4];
    const float* bq    = (const float*)d_in[5];
    const float* Wk    = (const float*)d_in[6];
    const float* bk    = (const float*)d_in[7];
    const float* wv    = (const float*)d_in[8];
    const float* bv    = (const float*)d_in[9];
    const float* th    = (const float*)d_in[10];
    float* out = (float*)d_out;

    hipLaunchKernelGGL(fused_v8, dim3(BB), dim3(256), 0, stream,
                       x, x_ids, tgp, cl, Wq, bq, Wk, bk, wv, bv, th, out);
}

// Round 11
// 54.868 us; speedup vs baseline: 1.2986x; 1.2986x over previous
//
#include <hip/hip_runtime.h>
#include <math.h>

#define BB 512
#define SS 200
#define DD 64
#define VV 100000

__device__ __forceinline__ float gauss_pdf(float xx, float mu, float sg) {
    float z = (xx - mu) / sg;
    return expf(-0.5f * z * z - logf(sg) - 0.9189385332046727f);
}

// tanh(x) = 1 - 2/(exp(2x)+1). Branch-free: exp->inf gives 1, exp->0 gives -1.
__device__ __forceinline__ float fast_tanh(float x) {
    float e = __expf(2.f * x);
    return 1.f - 2.f / (e + 1.f);
}

// v10 = v6 structure (best so far, 54.5us) + de-LDS'd GEMV.
// Round-5/6 decomposition: the GEMV was LDS-instruction-bound (8 waves/CU x
// 1024 broadcast ds_read_b128 x ~12cyc ~= 34us). Wq addresses are wave-
// uniform, so reading them from the GLOBAL pointer lets the compiler emit
// s_load -> SGPR-operand FMAs: scalar (lgkm) path, no LDS instrs, no vmcnt
// interaction with the in-flight zero-stores. GEMV becomes VALU-bound ~6us
// and fully hides under the ~31us store drain.
__global__ __launch_bounds__(256) void fused_v10(
    const float* __restrict__ x, const int* __restrict__ x_ids,
    const float* __restrict__ tg, const int* __restrict__ cla,
    const float* __restrict__ Wq, const float* __restrict__ bq,
    const float* __restrict__ Wk, const float* __restrict__ bk,
    const float* __restrict__ wv, const float* __restrict__ bv,
    const float* __restrict__ theta, float* __restrict__ out)
{
    const int b    = blockIdx.x;
    const int tid  = threadIdx.x;
    const int lane = tid & 63;
    const int wave = tid >> 6;

    __shared__ float sx0[DD];
    __shared__ float sKp[4][DD];
    __shared__ float sK[DD];
    __shared__ float sWv[DD];
    __shared__ float sScore[SS];
    __shared__ float sRed[8];
    __shared__ float sTh[17];

    const float* __restrict__ xb = x + (size_t)b * SS * DD;
    float* __restrict__ orow = out + (size_t)b * VV;

    // ---- this thread's x-row into 16 NAMED float4 regs (64 VGPRs) ----
    float4 xr0 = {0,0,0,0}, xr1 = {0,0,0,0}, xr2 = {0,0,0,0}, xr3 = {0,0,0,0},
           xr4 = {0,0,0,0}, xr5 = {0,0,0,0}, xr6 = {0,0,0,0}, xr7 = {0,0,0,0},
           xr8 = {0,0,0,0}, xr9 = {0,0,0,0}, xr10= {0,0,0,0}, xr11= {0,0,0,0},
           xr12= {0,0,0,0}, xr13= {0,0,0,0}, xr14= {0,0,0,0}, xr15= {0,0,0,0};
    if (tid < SS) {
        const float4* __restrict__ xp = (const float4*)(xb + tid * DD);
        xr0 = xp[0];  xr1 = xp[1];  xr2 = xp[2];  xr3 = xp[3];
        xr4 = xp[4];  xr5 = xp[5];  xr6 = xp[6];  xr7 = xp[7];
        xr8 = xp[8];  xr9 = xp[9];  xr10= xp[10]; xr11= xp[11];
        xr12= xp[12]; xr13= xp[13]; xr14= xp[14]; xr15= xp[15];
    }

    // ---- stage x0 / wv / theta (NO Wq staging anymore) ----
    if (tid < DD) sx0[tid] = xb[tid];
    if (tid >= 64 && tid < 128) sWv[tid - 64] = wv[tid - 64];
    if (tid >= 128 && tid < 145) sTh[tid - 128] = theta[tid - 128];
    __syncthreads();

    // ---- k partials: wave w covers j in [16w, 16w+16); lane = d ----
    {
        float acc = 0.f;
        #pragma unroll
        for (int jj = 0; jj < 16; ++jj) {
            int j = wave * 16 + jj;
            acc = fmaf(sx0[j], Wk[j * DD + lane], acc);
        }
        sKp[wave][lane] = acc;
    }
    __syncthreads();
    if (tid < DD)
        sK[tid] = sKp[0][tid] + sKp[1][tid] + sKp[2][tid] + sKp[3][tid]
                + bq[tid] + bk[tid];
    __syncthreads();
    // ======== no more barriers until after the GEMV ========

    // ---- zero this block's own 400 KB row FIRST (v6 order) ----
    // The wave fills its ~63-deep store queue, parks briefly, and the
    // remaining drain proceeds under the GEMV (which touches only SGPR/LDS
    // paths, no vmcnt). Pre-softmax barrier drains vmcnt(0) before atomics.
    {
        float4* __restrict__ orow4 = (float4*)orow;
        const float4 z4 = make_float4(0.f, 0.f, 0.f, 0.f);
        #pragma unroll 4
        for (int i = tid; i < VV / 4; i += 256) orow4[i] = z4;
    }

    // ---- fused GEMV + tanh + wv-dot: thread t owns s = t ----
    // Wq read directly from GLOBAL with wave-uniform indices -> s_load/SGPR.
    if (tid < SS) {
        const float4* __restrict__ W4 = (const float4*)Wq;  // [j][16 x float4]
        const float bvv = bv[0];
        float scacc = 0.f;
        for (int g = 0; g < 16; ++g) {        // d-group: d = 4g..4g+3
            float a0 = 0.f, a1 = 0.f, a2 = 0.f, a3 = 0.f;
#define STEP(J, XJ) { float4 w = W4[(J)*16 + g]; \
    a0 = fmaf(XJ, w.x, a0); a1 = fmaf(XJ, w.y, a1); \
    a2 = fmaf(XJ, w.z, a2); a3 = fmaf(XJ, w.w, a3); }
            STEP(0, xr0.x)  STEP(1, xr0.y)  STEP(2, xr0.z)  STEP(3, xr0.w)
            STEP(4, xr1.x)  STEP(5, xr1.y)  STEP(6, xr1.z)  STEP(7, xr1.w)
            STEP(8, xr2.x)  STEP(9, xr2.y)  STEP(10,xr2.z)  STEP(11,xr2.w)
            STEP(12,xr3.x)  STEP(13,xr3.y)  STEP(14,xr3.z)  STEP(15,xr3.w)
            STEP(16,xr4.x)  STEP(17,xr4.y)  STEP(18,xr4.z)  STEP(19,xr4.w)
            STEP(20,xr5.x)  STEP(21,xr5.y)  STEP(22,xr5.z)  STEP(23,xr5.w)
            STEP(24,xr6.x)  STEP(25,xr6.y)  STEP(26,xr6.z)  STEP(27,xr6.w)
            STEP(28,xr7.x)  STEP(29,xr7.y)  STEP(30,xr7.z)  STEP(31,xr7.w)
            STEP(32,xr8.x)  STEP(33,xr8.y)  STEP(34,xr8.z)  STEP(35,xr8.w)
            STEP(36,xr9.x)  STEP(37,xr9.y)  STEP(38,xr9.z)  STEP(39,xr9.w)
            STEP(40,xr10.x) STEP(41,xr10.y) STEP(42,xr10.z) STEP(43,xr10.w)
            STEP(44,xr11.x) STEP(45,xr11.y) STEP(46,xr11.z) STEP(47,xr11.w)
            STEP(48,xr12.x) STEP(49,xr12.y) STEP(50,xr12.z) STEP(51,xr12.w)
            STEP(52,xr13.x) STEP(53,xr13.y) STEP(54,xr13.z) STEP(55,xr13.w)
            STEP(56,xr14.x) STEP(57,xr14.y) STEP(58,xr14.z) STEP(59,xr14.w)
            STEP(60,xr15.x) STEP(61,xr15.y) STEP(62,xr15.z) STEP(63,xr15.w)
#undef STEP
            const int d = 4 * g;
            scacc = fmaf(fast_tanh(a0 + sK[d+0]), sWv[d+0], scacc);
            scacc = fmaf(fast_tanh(a1 + sK[d+1]), sWv[d+1], scacc);
            scacc = fmaf(fast_tanh(a2 + sK[d+2]), sWv[d+2], scacc);
            scacc = fmaf(fast_tanh(a3 + sK[d+3]), sWv[d+3], scacc);
        }
        int id = x_ids[b * SS + tid];
        sScore[tid] = (id == 0 || id == 1) ? -INFINITY : (scacc + bvv);
    }
    __syncthreads();   // scores ready AND this block's zero-stores drained

    // ---- block softmax over 200 scores (tid == s) ----
    float sc = (tid < SS) ? sScore[tid] : -INFINITY;
    float m = sc;
    #pragma unroll
    for (int off = 32; off > 0; off >>= 1) m = fmaxf(m, __shfl_xor(m, off));
    if (lane == 0) sRed[wave] = m;
    __syncthreads();
    const float M = fmaxf(fmaxf(sRed[0], sRed[1]), fmaxf(sRed[2], sRed[3]));
    float e = (tid < SS) ? expf(sc - M) : 0.f;
    float ssum = e;
    #pragma unroll
    for (int off = 32; off > 0; off >>= 1) ssum += __shfl_xor(ssum, off);
    if (lane == 0) sRed[4 + wave] = ssum;
    __syncthreads();
    const float Z = sRed[4] + sRed[5] + sRed[6] + sRed[7];

    const float wpg = sTh[6];

    // p_repeat scatter into this block's own (already-zeroed) row
    if (tid < SS && e > 0.f) {
        int id = x_ids[b * SS + tid];
        atomicAdd(orow + id, (1.f - wpg) * (e / Z));
    }

    // p_gap scatter at ids x_ids[:, 1:]
    if (tid < SS - 1) {
        float t  = tg[b * (SS - 1) + tid];
        int   c  = cla[b * (SS - 1) + tid];
        float c0 = (c == 0) ? t : 180.f;
        float c1 = (c == 1) ? t : 180.f;
        float c2 = (c == 2) ? t : 180.f;
        float g = sTh[0] * gauss_pdf(c0, sTh[7],  sTh[8])
                + sTh[1] * gauss_pdf(c1, sTh[9],  sTh[10])
                + sTh[2] * gauss_pdf(c1, sTh[11], sTh[12])
                + sTh[3] * gauss_pdf(c2, sTh[13], sTh[14])
                + sTh[4] * powf(c2, sTh[15]);
        int id = x_ids[b * SS + tid + 1];
        atomicAdd(orow + id, wpg * g);
    }
}

extern "C" void kernel_launch(void* const* d_in, const int* in_sizes, int n_in,
                              void* d_out, int out_size, void* d_ws, size_t ws_size,
                              hipStream_t stream) {
    const float* x     = (const float*)d_in[0];
    const int*   x_ids = (const int*)d_in[1];
    const float* tgp   = (const float*)d_in[2];
    const int*   cl    = (const int*)d_in[3];
    const float* Wq    = (const float*)d_in[4];
    const float* bq    = (const float*)d_in[5];
    const float* Wk    = (const float*)d_in[6];
    const float* bk    = (const float*)d_in[7];
    const float* wv    = (const float*)d_in[8];
    const float* bv    = (const float*)d_in[9];
    const float* th    = (const float*)d_in[10];
    float* out = (float*)d_out;

    hipLaunchKernelGGL(fused_v10, dim3(BB), dim3(256), 0, stream,
                       x, x_ids, tgp, cl, Wq, bq, Wk, bk, wv, bv, th, out);
}

// Round 12
// 43.395 us; speedup vs baseline: 1.6420x; 1.2644x over previous
//
#include <hip/hip_runtime.h>
#include <math.h>

#define BB 512
#define SS 200
#define DD 64
#define VV 100000
#define NT 320   // 5 waves: 0-3 compute, 4 stores

__device__ __forceinline__ float gauss_pdf(float xx, float mu, float sg) {
    float z = (xx - mu) / sg;
    return expf(-0.5f * z * z - logf(sg) - 0.9189385332046727f);
}

// tanh(x) = 1 - 2/(exp(2x)+1). Branch-free: exp->inf gives 1, exp->0 gives -1.
__device__ __forceinline__ float fast_tanh(float x) {
    float e = __expf(2.f * x);
    return 1.f - 2.f / (e + 1.f);
}

// v12: intra-block wave role-split with correct budgets (v8 retry).
// Waves 0-3: one s-row per thread, 64-VGPR x-row, Wq from LDS (LDS pipe is
// independent of the vmem queue -> immune to store backpressure).
// Wave 4: streams the block's 400 KB of zeros and parks at vmcnt backpressure,
// yielding all VALU issue slots to the compute waves (m114 mechanism).
// Pre-softmax __syncthreads re-merges: its per-wave vmcnt(0) commits the
// zeros before this block's atomics touch the row.
__global__ __launch_bounds__(NT, 2) void fused_v12(
    const float* __restrict__ x, const int* __restrict__ x_ids,
    const float* __restrict__ tg, const int* __restrict__ cla,
    const float* __restrict__ Wq, const float* __restrict__ bq,
    const float* __restrict__ Wk, const float* __restrict__ bk,
    const float* __restrict__ wv, const float* __restrict__ bv,
    const float* __restrict__ theta, float* __restrict__ out)
{
    const int b    = blockIdx.x;
    const int tid  = threadIdx.x;
    const int lane = tid & 63;
    const int wave = tid >> 6;

    __shared__ float sWq[DD * DD];   // 16 KB, row-major [j][d]
    __shared__ float sx0[DD];
    __shared__ float sKp[4][DD];
    __shared__ float sK[DD];
    __shared__ float sWv[DD];
    __shared__ float sScore[SS];
    __shared__ float sRed[8];
    __shared__ float sTh[17];

    const float* __restrict__ xb = x + (size_t)b * SS * DD;
    float* __restrict__ orow = out + (size_t)b * VV;

    // ---- compute threads' x-row into 16 NAMED float4 regs (64 VGPRs) ----
    float4 xr0 = {0,0,0,0}, xr1 = {0,0,0,0}, xr2 = {0,0,0,0}, xr3 = {0,0,0,0},
           xr4 = {0,0,0,0}, xr5 = {0,0,0,0}, xr6 = {0,0,0,0}, xr7 = {0,0,0,0},
           xr8 = {0,0,0,0}, xr9 = {0,0,0,0}, xr10= {0,0,0,0}, xr11= {0,0,0,0},
           xr12= {0,0,0,0}, xr13= {0,0,0,0}, xr14= {0,0,0,0}, xr15= {0,0,0,0};
    if (tid < SS) {
        const float4* __restrict__ xp = (const float4*)(xb + tid * DD);
        xr0 = xp[0];  xr1 = xp[1];  xr2 = xp[2];  xr3 = xp[3];
        xr4 = xp[4];  xr5 = xp[5];  xr6 = xp[6];  xr7 = xp[7];
        xr8 = xp[8];  xr9 = xp[9];  xr10= xp[10]; xr11= xp[11];
        xr12= xp[12]; xr13= xp[13]; xr14= xp[14]; xr15= xp[15];
    }

    // ---- stage Wq / x0 / wv / theta (all 320 threads) ----
    {
        const float4* __restrict__ Wq4 = (const float4*)Wq;
        float4* __restrict__ sWq4 = (float4*)sWq;
        for (int i = tid; i < 1024; i += NT) sWq4[i] = Wq4[i];
    }
    if (tid < DD) sx0[tid] = xb[tid];
    if (tid >= 64 && tid < 128) sWv[tid - 64] = wv[tid - 64];
    if (tid >= 128 && tid < 145) sTh[tid - 128] = theta[tid - 128];
    __syncthreads();

    // ---- k partials: waves 0-3, wave w covers j in [16w,16w+16); lane = d --
    if (wave < 4) {
        float acc = 0.f;
        #pragma unroll
        for (int jj = 0; jj < 16; ++jj) {
            int j = wave * 16 + jj;
            acc = fmaf(sx0[j], Wk[j * DD + lane], acc);
        }
        sKp[wave][lane] = acc;
    }
    __syncthreads();
    if (tid < DD)
        sK[tid] = sKp[0][tid] + sKp[1][tid] + sKp[2][tid] + sKp[3][tid]
                + bq[tid] + bk[tid];
    __syncthreads();
    // ======== roles diverge; re-merge at the pre-softmax barrier ========

    if (tid >= 256) {
        // ---- store role (wave 4): zero this block's 400 KB row ----
        float4* __restrict__ orow4 = (float4*)orow;
        const float4 z4 = make_float4(0.f, 0.f, 0.f, 0.f);
        for (int i = tid - 256; i < VV / 4; i += 64)
            orow4[i] = z4;
    } else if (tid < SS) {
        // ---- compute role: fused GEMV + tanh + wv-dot, thread t = row t ----
        const float4* __restrict__ W4 = (const float4*)sWq; // [j][16 x float4]
        const float bvv = bv[0];
        float scacc = 0.f;
        for (int g = 0; g < 16; ++g) {        // d-group: d = 4g..4g+3
            float a0 = 0.f, a1 = 0.f, a2 = 0.f, a3 = 0.f;
#define STEP(J, XJ) { float4 w = W4[(J)*16 + g]; \
    a0 = fmaf(XJ, w.x, a0); a1 = fmaf(XJ, w.y, a1); \
    a2 = fmaf(XJ, w.z, a2); a3 = fmaf(XJ, w.w, a3); }
            STEP(0, xr0.x)  STEP(1, xr0.y)  STEP(2, xr0.z)  STEP(3, xr0.w)
            STEP(4, xr1.x)  STEP(5, xr1.y)  STEP(6, xr1.z)  STEP(7, xr1.w)
            STEP(8, xr2.x)  STEP(9, xr2.y)  STEP(10,xr2.z)  STEP(11,xr2.w)
            STEP(12,xr3.x)  STEP(13,xr3.y)  STEP(14,xr3.z)  STEP(15,xr3.w)
            STEP(16,xr4.x)  STEP(17,xr4.y)  STEP(18,xr4.z)  STEP(19,xr4.w)
            STEP(20,xr5.x)  STEP(21,xr5.y)  STEP(22,xr5.z)  STEP(23,xr5.w)
            STEP(24,xr6.x)  STEP(25,xr6.y)  STEP(26,xr6.z)  STEP(27,xr6.w)
            STEP(28,xr7.x)  STEP(29,xr7.y)  STEP(30,xr7.z)  STEP(31,xr7.w)
            STEP(32,xr8.x)  STEP(33,xr8.y)  STEP(34,xr8.z)  STEP(35,xr8.w)
            STEP(36,xr9.x)  STEP(37,xr9.y)  STEP(38,xr9.z)  STEP(39,xr9.w)
            STEP(40,xr10.x) STEP(41,xr10.y) STEP(42,xr10.z) STEP(43,xr10.w)
            STEP(44,xr11.x) STEP(45,xr11.y) STEP(46,xr11.z) STEP(47,xr11.w)
            STEP(48,xr12.x) STEP(49,xr12.y) STEP(50,xr12.z) STEP(51,xr12.w)
            STEP(52,xr13.x) STEP(53,xr13.y) STEP(54,xr13.z) STEP(55,xr13.w)
            STEP(56,xr14.x) STEP(57,xr14.y) STEP(58,xr14.z) STEP(59,xr14.w)
            STEP(60,xr15.x) STEP(61,xr15.y) STEP(62,xr15.z) STEP(63,xr15.w)
#undef STEP
            const int d = 4 * g;
            scacc = fmaf(fast_tanh(a0 + sK[d+0]), sWv[d+0], scacc);
            scacc = fmaf(fast_tanh(a1 + sK[d+1]), sWv[d+1], scacc);
            scacc = fmaf(fast_tanh(a2 + sK[d+2]), sWv[d+2], scacc);
            scacc = fmaf(fast_tanh(a3 + sK[d+3]), sWv[d+3], scacc);
        }
        int id = x_ids[b * SS + tid];
        sScore[tid] = (id == 0 || id == 1) ? -INFINITY : (scacc + bvv);
    }
    __syncthreads();   // scores ready AND wave 4's zero-stores drained

    // ---- block softmax over 200 scores (tid == s); wave 4 rides along ----
    float sc = (tid < SS) ? sScore[tid] : -INFINITY;
    float m = sc;
    #pragma unroll
    for (int off = 32; off > 0; off >>= 1) m = fmaxf(m, __shfl_xor(m, off));
    if (lane == 0 && wave < 4) sRed[wave] = m;
    __syncthreads();
    const float M = fmaxf(fmaxf(sRed[0], sRed[1]), fmaxf(sRed[2], sRed[3]));
    float e = (tid < SS) ? expf(sc - M) : 0.f;
    float ssum = e;
    #pragma unroll
    for (int off = 32; off > 0; off >>= 1) ssum += __shfl_xor(ssum, off);
    if (lane == 0 && wave < 4) sRed[4 + wave] = ssum;
    __syncthreads();
    const float Z = sRed[4] + sRed[5] + sRed[6] + sRed[7];

    const float wpg = sTh[6];

    // p_repeat scatter into this block's own (already-zeroed) row
    if (tid < SS && e > 0.f) {
        int id = x_ids[b * SS + tid];
        atomicAdd(orow + id, (1.f - wpg) * (e / Z));
    }

    // p_gap scatter at ids x_ids[:, 1:]
    if (tid < SS - 1) {
        float t  = tg[b * (SS - 1) + tid];
        int   c  = cla[b * (SS - 1) + tid];
        float c0 = (c == 0) ? t : 180.f;
        float c1 = (c == 1) ? t : 180.f;
        float c2 = (c == 2) ? t : 180.f;
        float g = sTh[0] * gauss_pdf(c0, sTh[7],  sTh[8])
                + sTh[1] * gauss_pdf(c1, sTh[9],  sTh[10])
                + sTh[2] * gauss_pdf(c1, sTh[11], sTh[12])
                + sTh[3] * gauss_pdf(c2, sTh[13], sTh[14])
                + sTh[4] * powf(c2, sTh[15]);
        int id = x_ids[b * SS + tid + 1];
        atomicAdd(orow + id, wpg * g);
    }
}

extern "C" void kernel_launch(void* const* d_in, const int* in_sizes, int n_in,
                              void* d_out, int out_size, void* d_ws, size_t ws_size,
                              hipStream_t stream) {
    const float* x     = (const float*)d_in[0];
    const int*   x_ids = (const int*)d_in[1];
    const float* tgp   = (const float*)d_in[2];
    const int*   cl    = (const int*)d_in[3];
    const float* Wq    = (const float*)d_in[4];
    const float* bq    = (const float*)d_in[5];
    const float* Wk    = (const float*)d_in[6];
    const float* bk    = (const float*)d_in[7];
    const float* wv    = (const float*)d_in[8];
    const float* bv    = (const float*)d_in[9];
    const float* th    = (const float*)d_in[10];
    float* out = (float*)d_out;

    hipLaunchKernelGGL(fused_v12, dim3(BB), dim3(NT), 0, stream,
                       x, x_ids, tgp, cl, Wq, bq, Wk, bk, wv, bv, th, out);
}